// Round 9
// baseline (221.343 us; speedup 1.0000x reference)
//
#include <hip/hip_runtime.h>
#include <cstdint>
#include <cstddef>

using bf16x8 = __attribute__((ext_vector_type(8))) short;
using f32x4  = __attribute__((ext_vector_type(4))) float;

__device__ __forceinline__ unsigned short f2bf(float f) {
  unsigned int u = __builtin_bit_cast(unsigned int, f);
  u += 0x7FFFu + ((u >> 16) & 1u);   // round-to-nearest-even
  return (unsigned short)(u >> 16);
}
__device__ __forceinline__ float bf2f(unsigned int h16) {
  unsigned int u = h16 << 16;
  return __builtin_bit_cast(float, u);
}

__device__ __forceinline__ void gl_lds16(const void* g, void* l) {
  __builtin_amdgcn_global_load_lds(
      (const __attribute__((address_space(1))) unsigned int*)g,
      (__attribute__((address_space(3))) unsigned int*)l,
      16, 0, 0);
}

#define MFMA __builtin_amdgcn_mfma_f32_16x16x32_bf16

// C[m,n] = sum_{k in z-slice} A[m,k]*B[n,k]  (A: MxK, B: NxK, bf16 row-major)
// 3-stage LDS pipeline (prefetch distance 2), raw s_barrier + manual vmcnt.
// XOR bank swizzle on K-chunks (2-way = free).
// MODE 0: E=exp(scale[n]/(dist+0.1)) -> LDS-transposed coalesced bf16 store; row sums atomic to aux3
// MODE 2: bf16 store of c
// MODE 3: bf16 store of c into partial slice z
// SWZ 0: plain 2-D grid. SWZ 1: 2048 1-D, XCD owns 4-wide n-band.
// SWZ 4: 512 1-D, XCD owns 8 m-tiles x 8 (e,z) combos; concurrent 32-block set
//        per XCD covers 8 m x 4 e at one z -> shared E-halves L2-resident.
template<int MODE, int SWZ, int WM, int WN>
__global__ __launch_bounds__(WM* WN * 64)
void gemm_bt(const unsigned short* __restrict__ A,
             const unsigned short* __restrict__ B,
             void* __restrict__ Cv,
             int M, int N, int K, int KC,
             const float* __restrict__ aux0,
             const float* __restrict__ aux1,
             const float* __restrict__ aux2,
             float* __restrict__ aux3)
{
  constexpr int THREADS = WM * WN * 64;
  constexpr int BMt = WM * 64, BNt = WN * 64;
  constexpr int NA = BMt * 4 / THREADS;   // A 16B-chunks per thread per stage
  constexpr int NB = BNt * 4 / THREADS;
  constexpr int L  = NA + NB;
  constexpr int ASZ = BMt * 32, BSZ = BNt * 32;

  __shared__ unsigned short smem[3 * (ASZ + BSZ)];
  unsigned short* As = smem;
  unsigned short* Bs = smem + 3 * ASZ;

  const int tid  = threadIdx.x;
  const int lane = tid & 63;
  const int wv   = tid >> 6;
  const int wm   = (wv / WN) * 64;
  const int wn   = (wv % WN) * 64;
  const int l16  = lane & 15;
  const int quad = lane >> 4;
  const int sw   = (l16 >> 1) & 3;

  int xt, yt, zt;
  if (SWZ == 0) {
    xt = blockIdx.x; yt = blockIdx.y; zt = 0;
  } else if (SWZ == 1) {
    const int lin = blockIdx.x;
    const int xcd = lin & 7, per = lin >> 3;
    xt = xcd * 4 + (per & 3); yt = per >> 2; zt = 0;
  } else {                                  // SWZ 4
    const int lin = blockIdx.x;             // 512 blocks
    const int xcd = lin & 7, i = lin >> 3;  // i in [0,64)
    yt = xcd * 8 + (i & 7);                 // m-tile 0..63, octet pinned to XCD
    const int combo = i >> 3;               // 0..7
    xt = combo & 3;                         // e-tile
    zt = combo >> 2;                        // K half
  }

  const int n0 = xt * BNt;
  const int m0 = yt * BMt;
  const int kbeg = zt * KC;

  f32x4 acc[4][4];
#pragma unroll
  for (int i = 0; i < 4; ++i)
#pragma unroll
    for (int j = 0; j < 4; ++j) {
      f32x4 z = {0.f, 0.f, 0.f, 0.f};
      acc[i][j] = z;
    }

  const unsigned short* gA[NA]; int lA[NA];
  const unsigned short* gB[NB]; int lB[NB];
#pragma unroll
  for (int i = 0; i < NA; ++i) {
    const int c = tid + i * THREADS;
    const int row = c >> 2, col = ((c & 3) ^ ((c >> 3) & 3)) * 8;
    gA[i] = A + (size_t)(m0 + row) * K + col + kbeg;
    lA[i] = c * 8;
  }
#pragma unroll
  for (int i = 0; i < NB; ++i) {
    const int c = tid + i * THREADS;
    const int row = c >> 2, col = ((c & 3) ^ ((c >> 3) & 3)) * 8;
    gB[i] = B + (size_t)(n0 + row) * K + col + kbeg;
    lB[i] = c * 8;
  }

  auto issue = [&](int st, int kc) {
#pragma unroll
    for (int i = 0; i < NA; ++i) gl_lds16(gA[i] + kc, &As[st * ASZ + lA[i]]);
#pragma unroll
    for (int i = 0; i < NB; ++i) gl_lds16(gB[i] + kc, &Bs[st * BSZ + lB[i]]);
  };

  const int nk = KC >> 5;   // BK = 32
  issue(0, 0);
  if (nk > 1) issue(1, 32);

  int cur = 0, pf = 2;
  for (int it = 0; it < nk; ++it) {
    __builtin_amdgcn_s_barrier();
    if (it + 2 < nk) {
      issue(pf, (it + 2) << 5);
      __builtin_amdgcn_s_waitcnt(0x0F70 | (2 * L));
    } else if (it + 1 < nk) {
      __builtin_amdgcn_s_waitcnt(0x0F70 | L);
    } else {
      __builtin_amdgcn_s_waitcnt(0x0F70);
    }
    __builtin_amdgcn_s_barrier();

    bf16x8 af[4], bfr[4];
#pragma unroll
    for (int mi = 0; mi < 4; ++mi)
      af[mi] = *(const bf16x8*)&As[cur * ASZ + (wm + mi * 16 + l16) * 32 + (quad ^ sw) * 8];
#pragma unroll
    for (int ni = 0; ni < 4; ++ni)
      bfr[ni] = *(const bf16x8*)&Bs[cur * BSZ + (wn + ni * 16 + l16) * 32 + (quad ^ sw) * 8];
#pragma unroll
    for (int mi = 0; mi < 4; ++mi)
#pragma unroll
      for (int ni = 0; ni < 4; ++ni)
        acc[mi][ni] = MFMA(af[mi], bfr[ni], acc[mi][ni], 0, 0, 0);

    cur = (cur == 2) ? 0 : cur + 1;
    pf  = (pf == 2) ? 0 : pf + 1;
  }

  // ---- epilogue ----
  if constexpr (MODE == 0) {
    // (only instantiated with WM=WN=2, THREADS=256, BMt=BNt=128)
    float p2v[4], scv[4];
#pragma unroll
    for (int ni = 0; ni < 4; ++ni) {
      const int n = n0 + wn + ni * 16 + l16;
      p2v[ni] = aux1[n];
      scv[ni] = aux2[n] * 1.44269504088896f;   // fold log2(e)
    }
    __syncthreads();                            // done with K-loop LDS
    unsigned short* Es = smem;                  // 128 x (136-stride) bf16 tile
#pragma unroll
    for (int mi = 0; mi < 4; ++mi) {
#pragma unroll
      for (int r = 0; r < 4; ++r) {
        const int rowL = wm + mi * 16 + quad * 4 + r;
        const float rowa = aux0[m0 + rowL];
        float s = 0.f;
#pragma unroll
        for (int ni = 0; ni < 4; ++ni) {
          const int col = wn + ni * 16 + l16;
          const float v = acc[mi][ni][r];
          float sq   = fmaxf(rowa - 2.0f * v + p2v[ni], 0.0f);
          float dist = __builtin_amdgcn_sqrtf(sq);
          float e    = __builtin_amdgcn_exp2f(scv[ni] * __builtin_amdgcn_rcpf(dist + 0.1f));
          Es[rowL * 136 + col] = f2bf(e);
          s += e;                                // unrounded sum (rel err ~3e-5)
        }
        s += __shfl_down(s, 8);
        s += __shfl_down(s, 4);
        s += __shfl_down(s, 2);
        s += __shfl_down(s, 1);
        if (l16 == 0) unsafeAtomicAdd(&aux3[m0 + rowL], s);
      }
    }
    __syncthreads();
    unsigned short* Eg = (unsigned short*)Cv;
#pragma unroll
    for (int j = 0; j < 8; ++j) {               // coalesced 16B stores
      const int cid = j * 256 + tid;
      const int row = cid >> 4, c = cid & 15;
      bf16x8 v = *(const bf16x8*)&Es[row * 136 + c * 8];
      *(bf16x8*)&Eg[(size_t)(m0 + row) * N + n0 + c * 8] = v;
    }
  } else {
    unsigned short* Pz = (unsigned short*)Cv;
    if (MODE == 3) Pz += (size_t)zt * (size_t)M * N;
#pragma unroll
    for (int mi = 0; mi < 4; ++mi) {
#pragma unroll
      for (int r = 0; r < 4; ++r) {
        const int m = m0 + wm + mi * 16 + quad * 4 + r;
#pragma unroll
        for (int ni = 0; ni < 4; ++ni) {
          const int n = n0 + wn + ni * 16 + l16;
          Pz[(size_t)m * N + n] = f2bf(acc[mi][ni][r]);
        }
      }
    }
  }
}

// ===== prep_all: all conversions/norms/bias in ONE launch (3456 blocks) =====
__global__ void prep_all(const float* __restrict__ x, const float* __restrict__ positions,
                         const float* __restrict__ w_v, const float* __restrict__ w_o,
                         const float* __restrict__ b_v, const float* __restrict__ b_o,
                         unsigned short* __restrict__ xb, unsigned short* __restrict__ pb,
                         unsigned short* __restrict__ wvT, unsigned short* __restrict__ wob,
                         float* __restrict__ x2, float* __restrict__ p2,
                         float* __restrict__ bias2, float* __restrict__ denom)
{
  const int b = blockIdx.x;
  const int tid = threadIdx.x;
  const int lane = tid & 63;
  const int wv = tid >> 6;

  if (b < 3072) {
    const bool isx = (b < 2048);
    const int r = (isx ? b : b - 2048) * 4 + wv;
    const float* X = isx ? x : positions;
    unsigned short* Xb = isx ? xb : pb;
    const float4* row = (const float4*)(X + (size_t)r * 512);
    const float4 a = row[lane];
    const float4 c = row[lane + 64];
    ushort4 ua, uc;
    ua.x = f2bf(a.x); ua.y = f2bf(a.y); ua.z = f2bf(a.z); ua.w = f2bf(a.w);
    uc.x = f2bf(c.x); uc.y = f2bf(c.y); uc.z = f2bf(c.z); uc.w = f2bf(c.w);
    ushort4* orow = (ushort4*)(Xb + (size_t)r * 512);
    orow[lane] = ua;
    orow[lane + 64] = uc;
    float s = a.x*a.x + a.y*a.y + a.z*a.z + a.w*a.w
            + c.x*c.x + c.y*c.y + c.z*c.z + c.w*c.w;
#pragma unroll
    for (int off = 32; off > 0; off >>= 1) s += __shfl_down(s, off, 64);
    if (lane == 0) {
      if (isx) { x2[r] = s; denom[r] = 0.f; }
      else     { p2[r] = s; }
    }
  } else if (b < 3328) {
    const int i = (b - 3072) * 256 + tid;   // 65536
    float4 a = ((const float4*)w_o)[i];
    ushort4 ua;
    ua.x = f2bf(a.x); ua.y = f2bf(a.y); ua.z = f2bf(a.z); ua.w = f2bf(a.w);
    ((ushort4*)wob)[i] = ua;
    const int k = i >> 7, d4 = (i & 127) * 4;
    ushort4 t;
    t.x = f2bf(w_v[(size_t)(d4 + 0) * 512 + k]);
    t.y = f2bf(w_v[(size_t)(d4 + 1) * 512 + k]);
    t.z = f2bf(w_v[(size_t)(d4 + 2) * 512 + k]);
    t.w = f2bf(w_v[(size_t)(d4 + 3) * 512 + k]);
    ((ushort4*)wvT)[i] = t;                 // wvT[k][d] = wv[d][k]
  } else {
    const int e = (b - 3328) * 4 + wv;
    float s = 0.f;
#pragma unroll
    for (int j = 0; j < 8; ++j)
      s += w_o[(size_t)e * 512 + lane + j * 64] * b_v[lane + j * 64];
#pragma unroll
    for (int off = 32; off > 0; off >>= 1) s += __shfl_down(s, off, 64);
    if (lane == 0) bias2[e] = b_o[e] + s;   // softmax rows sum to 1
  }
}

// out[m,e] = (P0[m,e] + P1[m,e]) / denom[m] + bias2[e]   (P bf16, out fp32)
__global__ void reduce_out(const unsigned short* __restrict__ P,
                           const float* __restrict__ denom,
                           const float* __restrict__ bias2,
                           float* __restrict__ out) {
  const int i = blockIdx.x * 256 + threadIdx.x;   // 1,048,576 float4s
  const int m = i >> 7;
  const float rd = 1.0f / denom[m];
  const float4 b4 = ((const float4*)bias2)[i & 127];
  const ushort4 p0 = ((const ushort4*)P)[i];
  const ushort4 p1 = ((const ushort4*)P)[i + 1048576];
  float4 o;
  o.x = (bf2f(p0.x) + bf2f(p1.x)) * rd + b4.x;
  o.y = (bf2f(p0.y) + bf2f(p1.y)) * rd + b4.y;
  o.z = (bf2f(p0.z) + bf2f(p1.z)) * rd + b4.z;
  o.w = (bf2f(p0.w) + bf2f(p1.w)) * rd + b4.w;
  ((float4*)out)[i] = o;
}

extern "C" void kernel_launch(void* const* d_in, const int* in_sizes, int n_in,
                              void* d_out, int out_size, void* d_ws, size_t ws_size,
                              hipStream_t stream) {
  const float* x         = (const float*)d_in[0];
  const float* positions = (const float*)d_in[1];
  const float* scale     = (const float*)d_in[2];
  const float* w_v       = (const float*)d_in[3];
  const float* b_v       = (const float*)d_in[4];
  const float* w_o       = (const float*)d_in[5];
  const float* b_o       = (const float*)d_in[6];
  float* out = (float*)d_out;

  const int M = 8192, N = 4096, D = 512;

  char* base = (char*)d_ws;
  unsigned short* Eb    = (unsigned short*)(base + 0);          // 64 MB
  unsigned short* v2T   = (unsigned short*)(base + 67108864);   // 4 MB
  float*          denom = (float*)(base + 71303168);            // 32 KB
  float*          x2    = (float*)(base + 71335936);            // 32 KB
  float*          p2    = (float*)(base + 71368704);            // 16 KB
  float*          bias2 = (float*)(base + 71385088);            // 2 KB
  char* base2 = base + 71387136;
  unsigned short* part  = (unsigned short*)base2;               // 16 MB [MODE-3 .. reduce]
  unsigned short* xb    = (unsigned short*)base2;               // 8 MB  [prep .. MODE-0]
  unsigned short* pb    = (unsigned short*)(base2 + 8388608);   // 4 MB  [prep .. MODE-0]
  unsigned short* wvT_b = (unsigned short*)(base2 + 12582912);  // 0.5 MB
  unsigned short* wo_b  = (unsigned short*)(base2 + 13107200);  // 0.5 MB
  unsigned short* W2b   = (unsigned short*)(base2 + 13631488);  // 0.5 MB

  // all prep in one launch
  prep_all<<<3456, 256, 0, stream>>>(x, positions, w_v, w_o, b_v, b_o,
                                     xb, pb, wvT_b, wo_b, x2, p2, bias2, denom);

  // W2[e,k] = sum_d wo[e,d] wv[d,k]
  gemm_bt<2, 0, 2, 2><<<dim3(4, 4), 256, 0, stream>>>(
      wo_b, wvT_b, W2b, 512, 512, 512, 512, nullptr, nullptr, nullptr, nullptr);

  // v2T[e,n] = sum_k W2[e,k] p[n,k]
  gemm_bt<2, 0, 2, 2><<<dim3(32, 4), 256, 0, stream>>>(
      W2b, pb, v2T, 512, 4096, 512, 512, nullptr, nullptr, nullptr, nullptr);

  // E[m,n] = exp(scale[n]/(dist+0.1)); denom[m] += row sums
  gemm_bt<0, 1, 2, 2><<<2048, 256, 0, stream>>>(
      xb, pb, Eb, M, N, D, D, x2, p2, scale, denom);

  // part[z][m,e] = sum_{n in half z} E[m,n] v2T[e,n]
  // 512 blocks x 256 thr, tile 128x128, z=2 -> 2 blocks/CU
  gemm_bt<3, 4, 2, 2><<<512, 256, 0, stream>>>(
      Eb, v2T, part, M, D, N, N / 2, nullptr, nullptr, nullptr, nullptr);

  // out = (part0 + part1)/denom + bias2
  reduce_out<<<4096, 256, 0, stream>>>(part, denom, bias2, out);
}

// Round 10
// 219.729 us; speedup vs baseline: 1.0073x; 1.0073x over previous
//
#include <hip/hip_runtime.h>
#include <cstdint>
#include <cstddef>

using bf16x8 = __attribute__((ext_vector_type(8))) short;
using f32x4  = __attribute__((ext_vector_type(4))) float;

__device__ __forceinline__ unsigned short f2bf(float f) {
  unsigned int u = __builtin_bit_cast(unsigned int, f);
  u += 0x7FFFu + ((u >> 16) & 1u);   // round-to-nearest-even
  return (unsigned short)(u >> 16);
}
__device__ __forceinline__ float bf2f(unsigned int h16) {
  unsigned int u = h16 << 16;
  return __builtin_bit_cast(float, u);
}

__device__ __forceinline__ void gl_lds16(const void* g, void* l) {
  __builtin_amdgcn_global_load_lds(
      (const __attribute__((address_space(1))) unsigned int*)g,
      (__attribute__((address_space(3))) unsigned int*)l,
      16, 0, 0);
}

#define MFMA __builtin_amdgcn_mfma_f32_16x16x32_bf16

// C[m,n] = sum_{k in z-slice} A[m,k]*B[n,k]  (A: MxK, B: NxK, bf16 row-major)
// BK=64, 2-stage LDS double-buffer (prefetch distance 1), raw s_barrier +
// manual vmcnt. Halved iteration count vs BK=32 amortizes the per-barrier
// convoy overhead (~430cy/iter, invariant across rounds 4-9).
// LDS chunk map: row r, LDS chunk q holds global chunk q^(r&7)  (b128 reads
// 2-way bank aliased = free).
// MODE 0: E=exp(scale[n]/(dist+0.1)) -> LDS-transpose coalesced store; row sums atomic
// MODE 2: bf16 store of c
// MODE 3: bf16 store of c into partial slice z
// SWZ 0: plain 2-D grid. SWZ 1: 2048 1-D, XCD owns 4-wide n-band.
// SWZ 4: 512 1-D, XCD owns 8 m-tiles x 8 (e,z); E-slices L2-resident.
template<int MODE, int SWZ, int WM, int WN>
__global__ __launch_bounds__(WM* WN * 64)
void gemm_bt(const unsigned short* __restrict__ A,
             const unsigned short* __restrict__ B,
             void* __restrict__ Cv,
             int M, int N, int K, int KC,
             const float* __restrict__ aux0,
             const float* __restrict__ aux1,
             const float* __restrict__ aux2,
             float* __restrict__ aux3)
{
  constexpr int THREADS = WM * WN * 64;
  constexpr int BMt = WM * 64, BNt = WN * 64;
  constexpr int NA = BMt * 8 / THREADS;   // A 16B-chunks per thread per stage
  constexpr int NB = BNt * 8 / THREADS;
  constexpr int L  = NA + NB;
  constexpr int ASZ = BMt * 64, BSZ = BNt * 64;   // shorts per stage

  __shared__ unsigned short smem[2 * (ASZ + BSZ)];
  unsigned short* As = smem;
  unsigned short* Bs = smem + 2 * ASZ;

  const int tid  = threadIdx.x;
  const int lane = tid & 63;
  const int wv   = tid >> 6;
  const int wm   = (wv / WN) * 64;
  const int wn   = (wv % WN) * 64;
  const int l16  = lane & 15;
  const int quad = lane >> 4;

  int xt, yt, zt;
  if (SWZ == 0) {
    xt = blockIdx.x; yt = blockIdx.y; zt = 0;
  } else if (SWZ == 1) {
    const int lin = blockIdx.x;
    const int xcd = lin & 7, per = lin >> 3;
    xt = xcd * 4 + (per & 3); yt = per >> 2; zt = 0;
  } else {                                  // SWZ 4
    const int lin = blockIdx.x;             // 512 blocks
    const int xcd = lin & 7, i = lin >> 3;  // i in [0,64)
    yt = xcd * 8 + (i & 7);                 // m-tile octet pinned to XCD
    const int combo = i >> 3;               // 0..7
    xt = combo & 3;                         // e-tile
    zt = combo >> 2;                        // K half
  }

  const int n0 = xt * BNt;
  const int m0 = yt * BMt;
  const int kbeg = zt * KC;

  f32x4 acc[4][4];
#pragma unroll
  for (int i = 0; i < 4; ++i)
#pragma unroll
    for (int j = 0; j < 4; ++j) {
      f32x4 z = {0.f, 0.f, 0.f, 0.f};
      acc[i][j] = z;
    }

  // staging: LDS chunk c holds global chunk (c&7)^((c>>3)&7) of row c>>3
  const unsigned short* gA[NA]; int lA[NA];
  const unsigned short* gB[NB]; int lB[NB];
#pragma unroll
  for (int i = 0; i < NA; ++i) {
    const int c = tid + i * THREADS;
    const int row = c >> 3, col = ((c & 7) ^ (row & 7)) * 8;
    gA[i] = A + (size_t)(m0 + row) * K + col + kbeg;
    lA[i] = c * 8;
  }
#pragma unroll
  for (int i = 0; i < NB; ++i) {
    const int c = tid + i * THREADS;
    const int row = c >> 3, col = ((c & 7) ^ (row & 7)) * 8;
    gB[i] = B + (size_t)(n0 + row) * K + col + kbeg;
    lB[i] = c * 8;
  }

  auto issue = [&](int st, int kc) {
#pragma unroll
    for (int i = 0; i < NA; ++i) gl_lds16(gA[i] + kc, &As[st * ASZ + lA[i]]);
#pragma unroll
    for (int i = 0; i < NB; ++i) gl_lds16(gB[i] + kc, &Bs[st * BSZ + lB[i]]);
  };

  const int nk = KC >> 6;   // BK = 64
  issue(0, 0);

  int cur = 0;
  for (int it = 0; it < nk; ++it) {
    __builtin_amdgcn_s_barrier();            // prev readers done with buf[cur^1]
    if (it + 1 < nk) {
      issue(cur ^ 1, (it + 1) << 6);
      __builtin_amdgcn_s_waitcnt(0x0F70 | L);  // my buf[cur] landed; next in flight
    } else {
      __builtin_amdgcn_s_waitcnt(0x0F70);
    }
    __builtin_amdgcn_s_barrier();            // everyone's buf[cur] visible

#pragma unroll
    for (int ks = 0; ks < 2; ++ks) {
      bf16x8 af[4], bfr[4];
#pragma unroll
      for (int mi = 0; mi < 4; ++mi) {
        const int r = wm + mi * 16 + l16;
        af[mi] = *(const bf16x8*)&As[cur * ASZ + r * 64 + (((ks * 4 + quad) ^ (r & 7)) * 8)];
      }
#pragma unroll
      for (int ni = 0; ni < 4; ++ni) {
        const int r = wn + ni * 16 + l16;
        bfr[ni] = *(const bf16x8*)&Bs[cur * BSZ + r * 64 + (((ks * 4 + quad) ^ (r & 7)) * 8)];
      }
#pragma unroll
      for (int mi = 0; mi < 4; ++mi)
#pragma unroll
        for (int ni = 0; ni < 4; ++ni)
          acc[mi][ni] = MFMA(af[mi], bfr[ni], acc[mi][ni], 0, 0, 0);
    }
    cur ^= 1;
  }

  // ---- epilogue ----
  if constexpr (MODE == 0) {
    // (only instantiated with WM=WN=2, THREADS=256, BMt=BNt=128)
    float p2v[4], scv[4];
#pragma unroll
    for (int ni = 0; ni < 4; ++ni) {
      const int n = n0 + wn + ni * 16 + l16;
      p2v[ni] = aux1[n];
      scv[ni] = aux2[n] * 1.44269504088896f;   // fold log2(e)
    }
    __syncthreads();                            // done with K-loop LDS
    unsigned short* Es = smem;                  // 128 x (136-stride) bf16 tile
#pragma unroll
    for (int mi = 0; mi < 4; ++mi) {
#pragma unroll
      for (int r = 0; r < 4; ++r) {
        const int rowL = wm + mi * 16 + quad * 4 + r;
        const float rowa = aux0[m0 + rowL];
        float s = 0.f;
#pragma unroll
        for (int ni = 0; ni < 4; ++ni) {
          const int col = wn + ni * 16 + l16;
          const float v = acc[mi][ni][r];
          float sq   = fmaxf(rowa - 2.0f * v + p2v[ni], 0.0f);
          float dist = __builtin_amdgcn_sqrtf(sq);
          float e    = __builtin_amdgcn_exp2f(scv[ni] * __builtin_amdgcn_rcpf(dist + 0.1f));
          Es[rowL * 136 + col] = f2bf(e);
          s += e;                                // unrounded sum (rel err ~3e-5)
        }
        s += __shfl_down(s, 8);
        s += __shfl_down(s, 4);
        s += __shfl_down(s, 2);
        s += __shfl_down(s, 1);
        if (l16 == 0) unsafeAtomicAdd(&aux3[m0 + rowL], s);
      }
    }
    __syncthreads();
    unsigned short* Eg = (unsigned short*)Cv;
#pragma unroll
    for (int j = 0; j < 8; ++j) {               // coalesced 16B stores
      const int cid = j * 256 + tid;
      const int row = cid >> 4, c = cid & 15;
      bf16x8 v = *(const bf16x8*)&Es[row * 136 + c * 8];
      *(bf16x8*)&Eg[(size_t)(m0 + row) * N + n0 + c * 8] = v;
    }
  } else {
    unsigned short* Pz = (unsigned short*)Cv;
    if (MODE == 3) Pz += (size_t)zt * (size_t)M * N;
#pragma unroll
    for (int mi = 0; mi < 4; ++mi) {
#pragma unroll
      for (int r = 0; r < 4; ++r) {
        const int m = m0 + wm + mi * 16 + quad * 4 + r;
#pragma unroll
        for (int ni = 0; ni < 4; ++ni) {
          const int n = n0 + wn + ni * 16 + l16;
          Pz[(size_t)m * N + n] = f2bf(acc[mi][ni][r]);
        }
      }
    }
  }
}

// ===== prep_all: all conversions/norms/bias in ONE launch (3456 blocks) =====
// [0,2048): x rows -> xb,x2,denom=0 ; [2048,3072): p rows -> pb,p2 ;
// [3072,3328): wv,wo -> bf16 (straight) ; [3328,3456): bias2
__global__ void prep_all(const float* __restrict__ x, const float* __restrict__ positions,
                         const float* __restrict__ w_v, const float* __restrict__ w_o,
                         const float* __restrict__ b_v, const float* __restrict__ b_o,
                         unsigned short* __restrict__ xb, unsigned short* __restrict__ pb,
                         unsigned short* __restrict__ wvb, unsigned short* __restrict__ wob,
                         float* __restrict__ x2, float* __restrict__ p2,
                         float* __restrict__ bias2, float* __restrict__ denom)
{
  const int b = blockIdx.x;
  const int tid = threadIdx.x;
  const int lane = tid & 63;
  const int wv = tid >> 6;

  if (b < 3072) {
    const bool isx = (b < 2048);
    const int r = (isx ? b : b - 2048) * 4 + wv;
    const float* X = isx ? x : positions;
    unsigned short* Xb = isx ? xb : pb;
    const float4* row = (const float4*)(X + (size_t)r * 512);
    const float4 a = row[lane];
    const float4 c = row[lane + 64];
    ushort4 ua, uc;
    ua.x = f2bf(a.x); ua.y = f2bf(a.y); ua.z = f2bf(a.z); ua.w = f2bf(a.w);
    uc.x = f2bf(c.x); uc.y = f2bf(c.y); uc.z = f2bf(c.z); uc.w = f2bf(c.w);
    ushort4* orow = (ushort4*)(Xb + (size_t)r * 512);
    orow[lane] = ua;
    orow[lane + 64] = uc;
    float s = a.x*a.x + a.y*a.y + a.z*a.z + a.w*a.w
            + c.x*c.x + c.y*c.y + c.z*c.z + c.w*c.w;
#pragma unroll
    for (int off = 32; off > 0; off >>= 1) s += __shfl_down(s, off, 64);
    if (lane == 0) {
      if (isx) { x2[r] = s; denom[r] = 0.f; }
      else     { p2[r] = s; }
    }
  } else if (b < 3328) {
    const int i = (b - 3072) * 256 + tid;   // 65536 float4 each
    float4 a = ((const float4*)w_v)[i];
    float4 c = ((const float4*)w_o)[i];
    ushort4 ua, uc;
    ua.x = f2bf(a.x); ua.y = f2bf(a.y); ua.z = f2bf(a.z); ua.w = f2bf(a.w);
    uc.x = f2bf(c.x); uc.y = f2bf(c.y); uc.z = f2bf(c.z); uc.w = f2bf(c.w);
    ((ushort4*)wvb)[i] = ua;
    ((ushort4*)wob)[i] = uc;
  } else {
    const int e = (b - 3328) * 4 + wv;
    float s = 0.f;
#pragma unroll
    for (int j = 0; j < 8; ++j)
      s += w_o[(size_t)e * 512 + lane + j * 64] * b_v[lane + j * 64];
#pragma unroll
    for (int off = 32; off > 0; off >>= 1) s += __shfl_down(s, off, 64);
    if (lane == 0) bias2[e] = b_o[e] + s;   // softmax rows sum to 1
  }
}

// out[m,e] = (P0[m,e] + P1[m,e]) / denom[m] + bias2[e]   (P bf16, out fp32)
__global__ void reduce_out(const unsigned short* __restrict__ P,
                           const float* __restrict__ denom,
                           const float* __restrict__ bias2,
                           float* __restrict__ out) {
  const int i = blockIdx.x * 256 + threadIdx.x;   // 1,048,576 float4s
  const int m = i >> 7;
  const float rd = 1.0f / denom[m];
  const float4 b4 = ((const float4*)bias2)[i & 127];
  const ushort4 p0 = ((const ushort4*)P)[i];
  const ushort4 p1 = ((const ushort4*)P)[i + 1048576];
  float4 o;
  o.x = (bf2f(p0.x) + bf2f(p1.x)) * rd + b4.x;
  o.y = (bf2f(p0.y) + bf2f(p1.y)) * rd + b4.y;
  o.z = (bf2f(p0.z) + bf2f(p1.z)) * rd + b4.z;
  o.w = (bf2f(p0.w) + bf2f(p1.w)) * rd + b4.w;
  ((float4*)out)[i] = o;
}

extern "C" void kernel_launch(void* const* d_in, const int* in_sizes, int n_in,
                              void* d_out, int out_size, void* d_ws, size_t ws_size,
                              hipStream_t stream) {
  const float* x         = (const float*)d_in[0];
  const float* positions = (const float*)d_in[1];
  const float* scale     = (const float*)d_in[2];
  const float* w_v       = (const float*)d_in[3];
  const float* b_v       = (const float*)d_in[4];
  const float* w_o       = (const float*)d_in[5];
  const float* b_o       = (const float*)d_in[6];
  float* out = (float*)d_out;

  const int M = 8192, N = 4096, D = 512;

  char* base = (char*)d_ws;
  unsigned short* Eb    = (unsigned short*)(base + 0);          // 64 MB [MODE-0 .. MODE-3]
  unsigned short* val   = (unsigned short*)(base + 0);          // 4 MB, parks in Eb [val-GEMM .. v2T-GEMM]
  unsigned short* v2T   = (unsigned short*)(base + 67108864);   // 4 MB
  float*          denom = (float*)(base + 71303168);            // 32 KB
  float*          x2    = (float*)(base + 71335936);            // 32 KB
  float*          p2    = (float*)(base + 71368704);            // 16 KB
  float*          bias2 = (float*)(base + 71385088);            // 2 KB
  char* base2 = base + 71387136;
  unsigned short* part  = (unsigned short*)base2;               // 16 MB [MODE-3 .. reduce]
  unsigned short* xb    = (unsigned short*)base2;               // 8 MB  [prep .. MODE-0]
  unsigned short* pb    = (unsigned short*)(base2 + 8388608);   // 4 MB  [prep .. MODE-0]
  unsigned short* wvb   = (unsigned short*)(base2 + 12582912);  // 0.5 MB [prep .. val-GEMM]
  unsigned short* wo_b  = (unsigned short*)(base2 + 13107200);  // 0.5 MB [prep .. v2T-GEMM]

  // all prep in one launch
  prep_all<<<3456, 256, 0, stream>>>(x, positions, w_v, w_o, b_v, b_o,
                                     xb, pb, wvb, wo_b, x2, p2, bias2, denom);

  // val[n,d] = sum_k p[n,k] wv[d,k]
  gemm_bt<2, 0, 2, 2><<<dim3(4, 32), 256, 0, stream>>>(
      pb, wvb, val, 4096, 512, 512, 512, nullptr, nullptr, nullptr, nullptr);

  // v2T[e,n] = sum_d wo[e,d] val[n,d]
  gemm_bt<2, 0, 2, 2><<<dim3(32, 4), 256, 0, stream>>>(
      wo_b, val, v2T, 512, 4096, 512, 512, nullptr, nullptr, nullptr, nullptr);

  // E[m,n] = exp(scale[n]/(dist+0.1)); denom[m] += row sums
  gemm_bt<0, 1, 2, 2><<<2048, 256, 0, stream>>>(
      xb, pb, Eb, M, N, D, D, x2, p2, scale, denom);

  // part[z][m,e] = sum_{n in half z} E[m,n] v2T[e,n]
  gemm_bt<3, 4, 2, 2><<<512, 256, 0, stream>>>(
      Eb, v2T, part, M, D, N, N / 2, nullptr, nullptr, nullptr, nullptr);

  // out = (part0 + part1)/denom + bias2
  reduce_out<<<4096, 256, 0, stream>>>(part, denom, bias2, out);
}